// Round 13
// baseline (663.604 us; speedup 1.0000x reference)
//
#include <hip/hip_runtime.h>

// Linear attention (elu+1 feature map), B=4 S=4096 D=2048 H=16 dk=128.
// bf16 MFMA, fp32 accumulate.
// Round 13: GEMM — remove per-phase forced lgkmcnt(0)+sched_barrier pins
// (compiler emits counted lgkm waits; reads overlap MFMA head). All barriers
// and vmcnt gates unchanged. Tail: kvt partial-reduce via fp32 atomicAdd
// (drops the 67 MB part round-trip).

#define D_MODEL 2048
#define SEQ     4096
#define BATCH   4
#define HEADS   16
#define DKH     128
#define M_TOK   16384   // BATCH*SEQ
#define NBH     64      // BATCH*HEADS

using frag8 = __attribute__((ext_vector_type(8))) short;   // 8 bf16 (4 VGPRs)
using f32x4 = __attribute__((ext_vector_type(4))) float;   // 4 fp32 acc

typedef __attribute__((address_space(1))) const unsigned int g_u32;
typedef __attribute__((address_space(3))) unsigned int       l_u32;

__device__ __forceinline__ unsigned short f2bf(float f) {
  unsigned u = __float_as_uint(f);
  u = u + 0x7fffu + ((u >> 16) & 1u);   // round-to-nearest-even
  return (unsigned short)(u >> 16);
}
__device__ __forceinline__ float bf2f(unsigned short h) {
  return __uint_as_float(((unsigned)h) << 16);
}

// ---- fp32 -> bf16 convert, all 5 tensors in one launch ----------------------
__global__ __launch_bounds__(256) void convert_all_kernel(
    const float* __restrict__ x,  const float* __restrict__ wq,
    const float* __restrict__ wk, const float* __restrict__ wv,
    const float* __restrict__ wo,
    unsigned short* __restrict__ xb,  unsigned short* __restrict__ wqb,
    unsigned short* __restrict__ wkb, unsigned short* __restrict__ wvb,
    unsigned short* __restrict__ wob) {
  const int bb = blockIdx.x;
  const float* in;
  unsigned short* out;
  long i;
  if (bb < 32768) {
    in = x; out = xb; i = (long)bb * 256 + threadIdx.x;
  } else {
    const int t = bb - 32768, s = t >> 12, r = t & 4095;
    i = (long)r * 256 + threadIdx.x;
    if (s == 0)      { in = wq; out = wqb; }
    else if (s == 1) { in = wk; out = wkb; }
    else if (s == 2) { in = wv; out = wvb; }
    else             { in = wo; out = wob; }
  }
  float4 v = reinterpret_cast<const float4*>(in)[i];
  ushort4 o;
  o.x = f2bf(v.x); o.y = f2bf(v.y); o.z = f2bf(v.z); o.w = f2bf(v.w);
  reinterpret_cast<ushort4*>(out)[i] = o;
}

// ============================================================================
// 256x256x(BK=64) 8-phase GEMM (R7 structure, pins removed).
// 4 LDS slots (32KB = A 256x32 + B 256x32, XOR-swizzled). Tile 2i -> slots
// 0/1, tile 2i+1 -> slots 2/3. vmcnt(6) gates at ph3/ph7 only.
// ============================================================================

#define ST_B(GB, LD, SLOT, KC)                                                \
  _Pragma("unroll") for (int j_ = 0; j_ < 2; ++j_)                            \
    __builtin_amdgcn_global_load_lds(                                         \
        (g_u32*)((GB) + (srow + wid * 16 + j_ * 8 + (lane >> 3)) * (LD)       \
                 + (KC) + scg * 8),                                           \
        (l_u32*)(sh + (SLOT) * 16384 + 8192 + (wid * 16 + j_ * 8) * 64),      \
        16, 0, 0);

#define ST_A(GA, LD, SP, ST, KC)                                              \
    __builtin_amdgcn_global_load_lds(                                         \
        (g_u32*)((GA) + (srow + (ST) * 32 + (wid & 3) * 8 + (lane >> 3)) * (LD) \
                 + (KC) + (wid >> 2) * 32 + scg * 8),                         \
        (l_u32*)(sh + ((SP) + (wid >> 2)) * 16384 +                           \
                 ((ST) * 32 + (wid & 3) * 8) * 64),                           \
        16, 0, 0);

#define RD_A(S0, S1, Q)                                                       \
  a0[0] = *(const frag8*)(lds + (S0) * 16384 + tA + (Q) * 2048);              \
  a0[1] = *(const frag8*)(lds + (S0) * 16384 + tA + (Q) * 2048 + 1024);       \
  a1[0] = *(const frag8*)(lds + (S1) * 16384 + tA + (Q) * 2048);              \
  a1[1] = *(const frag8*)(lds + (S1) * 16384 + tA + (Q) * 2048 + 1024);

#define RD_B(D0, D1, S0, S1)                                                  \
  _Pragma("unroll") for (int n_ = 0; n_ < 4; ++n_) {                          \
    D0[n_] = *(const frag8*)(lds + (S0) * 16384 + tB + n_ * 1024);            \
    D1[n_] = *(const frag8*)(lds + (S1) * 16384 + tB + n_ * 1024);            \
  }

#define MM8(AQ, B0, B1)                                                       \
  __builtin_amdgcn_s_setprio(1);                                              \
  _Pragma("unroll") for (int j_ = 0; j_ < 2; ++j_)                            \
  _Pragma("unroll") for (int n_ = 0; n_ < 4; ++n_)                            \
    acc[(AQ) + j_][n_] = __builtin_amdgcn_mfma_f32_16x16x32_bf16(             \
        a0[j_], B0[n_], acc[(AQ) + j_][n_], 0, 0, 0);                         \
  _Pragma("unroll") for (int j_ = 0; j_ < 2; ++j_)                            \
  _Pragma("unroll") for (int n_ = 0; n_ < 4; ++n_)                            \
    acc[(AQ) + j_][n_] = __builtin_amdgcn_mfma_f32_16x16x32_bf16(             \
        a1[j_], B1[n_], acc[(AQ) + j_][n_], 0, 0, 0);                         \
  __builtin_amdgcn_s_setprio(0);

#define BAR __builtin_amdgcn_s_barrier()

// MODE: 0 = elu(v+bias[col])+1 -> bf16   (Q projection)
//       1 = elu(v+bias[row])+1 -> bf16, fused ksum (aux += row-sums)
//       2 = v+bias[row]        -> bf16   (V^T projection)
//       3 = v+bias[col]        -> f32    (final output projection)
template <int MODE, bool XMAJOR>
__global__ __launch_bounds__(512, 2) void gemm256_nt_kernel(
    const unsigned short* __restrict__ A, long lda,
    const unsigned short* __restrict__ Bm, long ldb,
    void* __restrict__ Cv, long ldc,
    const float* __restrict__ bias, float* __restrict__ aux, int K) {
  __shared__ unsigned short sh[65536];   // 128 KiB = 4 slots
  const int lane = threadIdx.x & 63, wid = threadIdx.x >> 6;
  const int wm = wid >> 2, wn = wid & 3;
  const int lr = lane & 15, lh = lane >> 4;

  // T1 bijective XCD swizzle
  const int gx = gridDim.x, gy = gridDim.y;
  const int cpx = (gx * gy) >> 3;
  const int P = blockIdx.y * gx + blockIdx.x;
  const int Lw = (P & 7) * cpx + (P >> 3);
  int bx, by;
  if (XMAJOR) { bx = Lw / gy; by = Lw - bx * gy; }
  else        { by = Lw / gx; bx = Lw - by * gx; }

  const long m0 = (long)by * 256, n0 = (long)bx * 256;
  const unsigned short* Ablk = A + m0 * lda;
  const unsigned short* Bblk = Bm + n0 * ldb;
  const int NT = K >> 6;

  const int qA = (wm * 4 + lh) ^ (lr & 7);
  const int qB = ((wn >> 1) * 4 + lh) ^ (lr & 7);
  const unsigned short* lds = sh;
  const int tA = lr * 64 + qA * 8;
  const int tB = 8192 + ((wn & 1) * 64 + lr) * 64 + qB * 8;

  const int sqd = (lane & 7) ^ (lane >> 3);
  const int scg = sqd & 3;
  const long srow = (long)((sqd >> 2) * 128);

  f32x4 acc[8][4];
#pragma unroll
  for (int m = 0; m < 8; ++m)
#pragma unroll
    for (int n = 0; n < 4; ++n) acc[m][n] = (f32x4){0.f, 0.f, 0.f, 0.f};

  frag8 a0[2], a1[2], bu0[4], bu1[4], bv0[4], bv1[4];

  // prologue: tile 0 complete (8 units), tile 1 all but A-strips 2,3
  ST_B(Bblk, ldb, 0, 0)
  ST_B(Bblk, ldb, 1, 32)
  ST_A(Ablk, lda, 0, 0, 0) ST_A(Ablk, lda, 0, 1, 0)
  ST_A(Ablk, lda, 0, 2, 0) ST_A(Ablk, lda, 0, 3, 0)
  if (NT > 1) {
    ST_B(Bblk, ldb, 2, 64)
    ST_B(Bblk, ldb, 3, 96)
    ST_A(Ablk, lda, 2, 0, 64) ST_A(Ablk, lda, 2, 1, 64)
  }
  asm volatile("s_waitcnt vmcnt(6)" ::: "memory");   // tile 0 landed
  BAR;

  const int NI = NT >> 1;
  for (int i = 0; i < NI; ++i) {
    const int kv = i * 128 + 64, kw = i * 128 + 128, kx = i * 128 + 192;
    const bool wok = (i + 1) < NI;
    // ---- ph0: tile u (slots 0,1) quadrant 0 ----
    RD_A(0, 1, 0)
    RD_B(bu0, bu1, 0, 1)
    ST_A(Ablk, lda, 2, 2, kv) ST_A(Ablk, lda, 2, 3, kv)
    asm volatile("s_waitcnt lgkmcnt(8)" ::: "memory");
    BAR;
    MM8(0, bu0, bu1)
    BAR;
    // ---- ph1: u q1 ----
    RD_A(0, 1, 1)
    if (wok) { ST_B(Bblk, ldb, 0, kw) }
    BAR;
    MM8(2, bu0, bu1)
    BAR;
    // ---- ph2: u q2 ----
    RD_A(0, 1, 2)
    if (wok) { ST_B(Bblk, ldb, 1, kw + 32) }
    BAR;
    MM8(4, bu0, bu1)
    BAR;
    // ---- ph3: u q3 ; vmcnt gate for tile v ----
    RD_A(0, 1, 3)
    if (wok) { ST_A(Ablk, lda, 0, 0, kw) ST_A(Ablk, lda, 0, 1, kw) }
    if (wok) asm volatile("s_waitcnt vmcnt(6)" ::: "memory");
    else     asm volatile("s_waitcnt vmcnt(0)" ::: "memory");
    BAR;
    MM8(6, bu0, bu1)
    BAR;
    // ---- ph4: tile v (slots 2,3) quadrant 0 ----
    RD_A(2, 3, 0)
    RD_B(bv0, bv1, 2, 3)
    if (wok) { ST_A(Ablk, lda, 0, 2, kw) ST_A(Ablk, lda, 0, 3, kw) }
    asm volatile("s_waitcnt lgkmcnt(8)" ::: "memory");
    BAR;
    MM8(0, bv0, bv1)
    BAR;
    // ---- ph5: v q1 ----
    RD_A(2, 3, 1)
    if (wok) { ST_B(Bblk, ldb, 2, kx) }
    BAR;
    MM8(2, bv0, bv1)
    BAR;
    // ---- ph6: v q2 ----
    RD_A(2, 3, 2)
    if (wok) { ST_B(Bblk, ldb, 3, kx + 32) }
    BAR;
    MM8(4, bv0, bv1)
    BAR;
    // ---- ph7: v q3 ; vmcnt gate for tile w (next iter) ----
    RD_A(2, 3, 3)
    if (wok) { ST_A(Ablk, lda, 2, 0, kx) ST_A(Ablk, lda, 2, 1, kx)
               asm volatile("s_waitcnt vmcnt(6)" ::: "memory"); }
    BAR;
    MM8(6, bv0, bv1)
    BAR;
  }

  // ---- epilogue (acc[m]: rows (m>>1)*32 + (m&1)*16 of the wave's 128) ----
  if constexpr (MODE == 1) {
    __shared__ float red2[256];
    if (threadIdx.x < 256) red2[threadIdx.x] = 0.f;
    __syncthreads();
#pragma unroll
    for (int m = 0; m < 8; ++m)
#pragma unroll
      for (int r = 0; r < 4; ++r) {
        const int lrow = wm * 128 + (m >> 1) * 32 + (m & 1) * 16 + lh * 4 + r;
        const long row = m0 + lrow;
        float part = 0.f;
#pragma unroll
        for (int n = 0; n < 4; ++n) {
          long col = n0 + wn * 64 + n * 16 + lr;
          float v = acc[m][n][r] + bias[row];
          v = v > 0.f ? v + 1.f : __expf(v);
          unsigned short us = f2bf(v);
          ((unsigned short*)Cv)[row * ldc + col] = us;
          part += bf2f(us);
        }
#pragma unroll
        for (int s = 1; s < 16; s <<= 1) part += __shfl_xor(part, s);
        if (lr == 0) atomicAdd(&red2[lrow], part);
      }
    __syncthreads();
    if (threadIdx.x < 256)
      atomicAdd(&aux[(n0 >> 12) * 2048 + m0 + threadIdx.x], red2[threadIdx.x]);
  } else {
#pragma unroll
    for (int m = 0; m < 8; ++m)
#pragma unroll
      for (int n = 0; n < 4; ++n)
#pragma unroll
        for (int r = 0; r < 4; ++r) {
          long row = m0 + wm * 128 + (m >> 1) * 32 + (m & 1) * 16 + lh * 4 + r;
          long col = n0 + wn * 64 + n * 16 + lr;
          float v = acc[m][n][r];
          if (MODE == 0) {
            v += bias[col]; v = v > 0.f ? v + 1.f : __expf(v);
            ((unsigned short*)Cv)[row * ldc + col] = f2bf(v);
          } else if (MODE == 2) {
            v += bias[row];
            ((unsigned short*)Cv)[row * ldc + col] = f2bf(v);
          } else {
            v += bias[col];
            ((float*)Cv)[row * ldc + col] = v;
          }
        }
  }
}

// ============================================================================
// 128x128 path (attention core).
// ============================================================================
__device__ __forceinline__ void stage_tile(const unsigned short* __restrict__ G,
                                           long ld, unsigned short* __restrict__ L) {
  const int w = threadIdx.x >> 6, l = threadIdx.x & 63;
#pragma unroll
  for (int r = 0; r < 4; ++r) {
    const int chunk = w * 4 + r;
    const int row = chunk * 8 + (l >> 3);
    const int col = (l & 7) * 8;
    __builtin_amdgcn_global_load_lds((g_u32*)(G + (long)row * ld + col),
                                     (l_u32*)(L + chunk * 512), 16, 0, 0);
  }
}

__device__ __forceinline__ void gemm_mainloop(const unsigned short* __restrict__ A, long lda,
                                              const unsigned short* __restrict__ B, long ldb,
                                              int K, unsigned short* lA, unsigned short* lB,
                                              f32x4 acc[4][4]) {
  const int lane = threadIdx.x & 63;
  const int wid  = threadIdx.x >> 6;
  const int wr = wid >> 1, wc = wid & 1;
  const int lr = lane & 15, lh = lane >> 4;
  for (int k0 = 0; k0 < K; k0 += 64) {
    stage_tile(A + k0, lda, lA);
    stage_tile(B + k0, ldb, lB);
    __syncthreads();
#pragma unroll
    for (int kk = 0; kk < 64; kk += 32) {
      frag8 av[4], bv[4];
#pragma unroll
      for (int m = 0; m < 4; ++m)
        av[m] = *reinterpret_cast<const frag8*>(lA + (wr * 64 + m * 16 + lr) * 64 + kk + lh * 8);
#pragma unroll
      for (int n = 0; n < 4; ++n)
        bv[n] = *reinterpret_cast<const frag8*>(lB + (wc * 64 + n * 16 + lr) * 64 + kk + lh * 8);
#pragma unroll
      for (int m = 0; m < 4; ++m)
#pragma unroll
        for (int n = 0; n < 4; ++n)
          acc[m][n] = __builtin_amdgcn_mfma_f32_16x16x32_bf16(av[m], bv[n], acc[m][n], 0, 0, 0);
    }
    __syncthreads();
  }
}

#define ACC_INIT(acc)                                   \
  _Pragma("unroll") for (int m_ = 0; m_ < 4; ++m_)      \
  _Pragma("unroll") for (int n_ = 0; n_ < 4; ++n_)      \
      acc[m_][n_] = (f32x4){0.f, 0.f, 0.f, 0.f};

// ---- KV^T partials: atomicAdd fp32 reduce (part buffer eliminated) ---------
__global__ __launch_bounds__(256) void kvt_partial_kernel(
    const unsigned short* __restrict__ VT, const unsigned short* __restrict__ KT,
    float* __restrict__ kvtf) {
  __shared__ unsigned short lA[128 * 64], lB[128 * 64];
  const int z = blockIdx.x;            // 0..511 = bh*8 + chunk
  const int bh = z >> 3, c = z & 7;
  const int b = bh >> 4, h = bh & 15;
  const long tOff = (long)b * SEQ + (long)c * 512;
  const unsigned short* A  = VT + (long)(h * DKH) * M_TOK + tOff;
  const unsigned short* Bm = KT + (long)(h * DKH) * M_TOK + tOff;
  f32x4 acc[4][4];
  ACC_INIT(acc);
  gemm_mainloop(A, M_TOK, Bm, M_TOK, 512, lA, lB, acc);
  const int lane = threadIdx.x & 63, wid = threadIdx.x >> 6;
  const int wr = wid >> 1, wc = wid & 1, lr = lane & 15, lh = lane >> 4;
  float* out = kvtf + (long)bh * (DKH * DKH);
#pragma unroll
  for (int m = 0; m < 4; ++m)
#pragma unroll
    for (int n = 0; n < 4; ++n)
#pragma unroll
      for (int r = 0; r < 4; ++r) {
        int row = wr * 64 + m * 16 + lh * 4 + r;   // e
        int col = wc * 64 + n * 16 + lr;           // d
        atomicAdd(&out[row * DKH + col], acc[m][n][r]);
      }
}

__global__ __launch_bounds__(256) void convert_kvt_kernel(
    const float* __restrict__ kvtf, unsigned short* __restrict__ kvt) {
  int i = blockIdx.x * 256 + threadIdx.x;          // over 64*16384 / 4
  float4 v = reinterpret_cast<const float4*>(kvtf)[i];
  ushort4 o;
  o.x = f2bf(v.x); o.y = f2bf(v.y); o.z = f2bf(v.z); o.w = f2bf(v.w);
  reinterpret_cast<ushort4*>(kvt)[i] = o;
}

// ---- QKV + fused qsum, 4 m-tiles per block ---------------------------------
__global__ __launch_bounds__(256) void qkv_kernel(const unsigned short* __restrict__ Q,
                                                  const unsigned short* __restrict__ KVT,
                                                  const float* __restrict__ ksum,
                                                  unsigned short* __restrict__ attn) {
  __shared__ unsigned short lA[2][128 * 64], lB[2][128 * 64];
  __shared__ float qs[128];
  const int z = blockIdx.y, b = z >> 4, h = z & 15;
  const long mbase = (long)blockIdx.x * 512;
  const unsigned short* Bm = KVT + (long)z * (DKH * DKH);
  const float* ks = ksum + (long)b * 2048 + h * DKH;
  const int lane = threadIdx.x & 63, wid = threadIdx.x >> 6;
  const int wr = wid >> 1, wc = wid & 1, lr = lane & 15, lh = lane >> 4;
  const int qrow = threadIdx.x >> 1, qhalf = threadIdx.x & 1;

  stage_tile(Bm,      DKH, lB[0]);
  stage_tile(Bm + 64, DKH, lB[1]);

  for (int mt = 0; mt < 4; ++mt) {
    const unsigned short* A = Q + ((long)b * SEQ + mbase + mt * 128) * D_MODEL + h * DKH;
    stage_tile(A,      D_MODEL, lA[0]);
    stage_tile(A + 64, D_MODEL, lA[1]);
    __syncthreads();   // A-tile (and B on first iter) visible to all
    float qacc = 0.f;
    {
      const unsigned* pr = (const unsigned*)(lA[qhalf] + qrow * 64);
      const float* kk = ks + qhalf * 64;
#pragma unroll
      for (int j = 0; j < 32; ++j) {
        unsigned u = pr[j];
        qacc += bf2f((unsigned short)(u & 0xffff)) * kk[2 * j] +
                bf2f((unsigned short)(u >> 16)) * kk[2 * j + 1];
      }
    }
    qacc += __shfl_xor(qacc, 1);
    if (qhalf == 0) qs[qrow] = qacc;
    f32x4 acc[4][4];
    ACC_INIT(acc);
#pragma unroll
    for (int hf = 0; hf < 2; ++hf)
#pragma unroll
      for (int kk2 = 0; kk2 < 64; kk2 += 32) {
        frag8 av[4], bv[4];
#pragma unroll
        for (int m = 0; m < 4; ++m)
          av[m] = *reinterpret_cast<const frag8*>(lA[hf] + (wr * 64 + m * 16 + lr) * 64 + kk2 + lh * 8);
#pragma unroll
        for (int n = 0; n < 4; ++n)
          bv[n] = *reinterpret_cast<const frag8*>(lB[hf] + (wc * 64 + n * 16 + lr) * 64 + kk2 + lh * 8);
#pragma unroll
        for (int m = 0; m < 4; ++m)
#pragma unroll
          for (int n = 0; n < 4; ++n)
            acc[m][n] = __builtin_amdgcn_mfma_f32_16x16x32_bf16(av[m], bv[n], acc[m][n], 0, 0, 0);
      }
    __syncthreads();   // qs visible; all lA reads complete (safe to restage)
#pragma unroll
    for (int m = 0; m < 4; ++m)
#pragma unroll
      for (int n = 0; n < 4; ++n)
#pragma unroll
        for (int r = 0; r < 4; ++r) {
          const int lrow = wr * 64 + m * 16 + lh * 4 + r;
          const long row = mbase + mt * 128 + lrow;        // s in [0,4096)
          const int col = wc * 64 + n * 16 + lr;           // e in [0,128)
          float dnm = qs[lrow] + 1e-8f;
          float v = acc[m][n][r] / dnm;
          attn[((long)b * SEQ + row) * D_MODEL + h * DKH + col] = f2bf(v);
        }
  }
}

// ---- workspace layout (bytes) ----------------------------------------------
#define OFF_XB   0L
#define OFF_WQ   (OFF_XB + (long)M_TOK * D_MODEL * 2)
#define OFF_WK   (OFF_WQ + (long)D_MODEL * D_MODEL * 2)
#define OFF_WV   (OFF_WK + (long)D_MODEL * D_MODEL * 2)
#define OFF_WO   (OFF_WV + (long)D_MODEL * D_MODEL * 2)
#define OFF_QB   (OFF_WO + (long)D_MODEL * D_MODEL * 2)
#define OFF_KT   (OFF_QB + (long)M_TOK * D_MODEL * 2)
#define OFF_VT   (OFF_KT + (long)M_TOK * D_MODEL * 2)
#define OFF_KVTF (OFF_VT + (long)M_TOK * D_MODEL * 2)          // fp32, 4 MB
#define OFF_KVT  (OFF_KVTF + (long)NBH * DKH * DKH * 4)
#define OFF_KSUM (OFF_KVT + (long)NBH * DKH * DKH * 2)
#define OFF_ATTN OFF_XB   // alias: x_bf16 dead after V^T projection

extern "C" void kernel_launch(void* const* d_in, const int* in_sizes, int n_in,
                              void* d_out, int out_size, void* d_ws, size_t ws_size,
                              hipStream_t stream) {
  const float* x  = (const float*)d_in[0];
  const float* wq = (const float*)d_in[1];
  const float* bq = (const float*)d_in[2];
  const float* wk = (const float*)d_in[3];
  const float* bk = (const float*)d_in[4];
  const float* wv = (const float*)d_in[5];
  const float* bv = (const float*)d_in[6];
  const float* wo = (const float*)d_in[7];
  const float* bo = (const float*)d_in[8];

  char* ws = (char*)d_ws;
  unsigned short* xb   = (unsigned short*)(ws + OFF_XB);
  unsigned short* wqb  = (unsigned short*)(ws + OFF_WQ);
  unsigned short* wkb  = (unsigned short*)(ws + OFF_WK);
  unsigned short* wvb  = (unsigned short*)(ws + OFF_WV);
  unsigned short* wob  = (unsigned short*)(ws + OFF_WO);
  unsigned short* Qb   = (unsigned short*)(ws + OFF_QB);
  unsigned short* KTb  = (unsigned short*)(ws + OFF_KT);
  unsigned short* VTb  = (unsigned short*)(ws + OFF_VT);
  float*          kvtf = (float*)(ws + OFF_KVTF);
  unsigned short* KVTb = (unsigned short*)(ws + OFF_KVT);
  float*          ksum = (float*)(ws + OFF_KSUM);
  unsigned short* attn = (unsigned short*)(ws + OFF_ATTN);

  dim3 blk(256);
  dim3 blk5(512);

  // fp32 -> bf16, all tensors in one launch
  convert_all_kernel<<<49152, blk, 0, stream>>>(x, wq, wk, wv, wo,
                                                xb, wqb, wkb, wvb, wob);

  // zero accumulators (ksum 32 KB, kvtf 4 MB)
  hipMemsetAsync(ksum, 0, NBH * DKH * sizeof(float), stream);
  hipMemsetAsync(kvtf, 0, (long)NBH * DKH * DKH * sizeof(float), stream);

  // Q = elu(x@Wq^T + bq)+1   (lean epilogue)
  gemm256_nt_kernel<0, false><<<dim3(D_MODEL / 256, M_TOK / 256), blk5, 0, stream>>>(
      xb, D_MODEL, wqb, D_MODEL, Qb, D_MODEL, bq, nullptr, D_MODEL);
  // K^T = elu(Wk@x^T + bk)+1  (2048 x M_TOK), fused ksum
  gemm256_nt_kernel<1, true><<<dim3(M_TOK / 256, D_MODEL / 256), blk5, 0, stream>>>(
      wkb, D_MODEL, xb, D_MODEL, KTb, M_TOK, bk, ksum, D_MODEL);
  // V^T = Wv@x^T + bv
  gemm256_nt_kernel<2, true><<<dim3(M_TOK / 256, D_MODEL / 256), blk5, 0, stream>>>(
      wvb, D_MODEL, xb, D_MODEL, VTb, M_TOK, bv, nullptr, D_MODEL);

  // KV^T per (b,h): split-K partials reduced via fp32 atomicAdd, then bf16
  kvt_partial_kernel<<<512, blk, 0, stream>>>(VTb, KTb, kvtf);
  convert_kvt_kernel<<<(NBH * DKH * DKH / 4) / 256, blk, 0, stream>>>(kvtf, KVTb);

  // attn = (Q @ KV) / (Q . Ksum + 1e-8)   -> bf16 (aliases xb); qsum fused
  qkv_kernel<<<dim3(SEQ / 512, NBH), blk, 0, stream>>>(Qb, KVTb, ksum, attn);

  // out = attn @ Wo^T + bo  -> fp32
  gemm256_nt_kernel<3, false><<<dim3(D_MODEL / 256, M_TOK / 256), blk5, 0, stream>>>(
      attn, D_MODEL, wob, D_MODEL, d_out, D_MODEL, bo, nullptr, D_MODEL);
}

// Round 16
// 652.465 us; speedup vs baseline: 1.0171x; 1.0171x over previous
//
#include <hip/hip_runtime.h>

// Linear attention (elu+1 feature map), B=4 S=4096 D=2048 H=16 dk=128.
// bf16 MFMA, fp32 accumulate.
// Round 16: revert to R12 exactly (best-known-good, 654 us). A-direct GEMM
// (R14/R15) abandoned: hand-counted vmcnt gates are unsound when the
// compiler emits scratch spill/fill (also vmcnt-counted) — replay-only race.
// R12 = R7 8-phase GEMM + fused ksum (MODE1) + qkv 4-tile/block with fused
// qsum + merged converts.

#define D_MODEL 2048
#define SEQ     4096
#define BATCH   4
#define HEADS   16
#define DKH     128
#define M_TOK   16384   // BATCH*SEQ
#define NBH     64      // BATCH*HEADS

using frag8 = __attribute__((ext_vector_type(8))) short;   // 8 bf16 (4 VGPRs)
using f32x4 = __attribute__((ext_vector_type(4))) float;   // 4 fp32 acc

typedef __attribute__((address_space(1))) const unsigned int g_u32;
typedef __attribute__((address_space(3))) unsigned int       l_u32;

__device__ __forceinline__ unsigned short f2bf(float f) {
  unsigned u = __float_as_uint(f);
  u = u + 0x7fffu + ((u >> 16) & 1u);   // round-to-nearest-even
  return (unsigned short)(u >> 16);
}
__device__ __forceinline__ float bf2f(unsigned short h) {
  return __uint_as_float(((unsigned)h) << 16);
}

// ---- fp32 -> bf16 convert, all 5 tensors in one launch ----------------------
// blocks [0, 32768): x (8388608 float4s); then 4 segments of 4096 blocks each
// for wq, wk, wv, wo (1048576 float4s each).
__global__ __launch_bounds__(256) void convert_all_kernel(
    const float* __restrict__ x,  const float* __restrict__ wq,
    const float* __restrict__ wk, const float* __restrict__ wv,
    const float* __restrict__ wo,
    unsigned short* __restrict__ xb,  unsigned short* __restrict__ wqb,
    unsigned short* __restrict__ wkb, unsigned short* __restrict__ wvb,
    unsigned short* __restrict__ wob) {
  const int bb = blockIdx.x;
  const float* in;
  unsigned short* out;
  long i;
  if (bb < 32768) {
    in = x; out = xb; i = (long)bb * 256 + threadIdx.x;
  } else {
    const int t = bb - 32768, s = t >> 12, r = t & 4095;
    i = (long)r * 256 + threadIdx.x;
    if (s == 0)      { in = wq; out = wqb; }
    else if (s == 1) { in = wk; out = wkb; }
    else if (s == 2) { in = wv; out = wvb; }
    else             { in = wo; out = wob; }
  }
  float4 v = reinterpret_cast<const float4*>(in)[i];
  ushort4 o;
  o.x = f2bf(v.x); o.y = f2bf(v.y); o.z = f2bf(v.z); o.w = f2bf(v.w);
  reinterpret_cast<ushort4*>(out)[i] = o;
}

// ============================================================================
// 256x256x(BK=64) 8-phase GEMM (R7 structure), C = A(256xK)*B(256xK)^T.
// 4 LDS slots (32KB = A 256x32 + B 256x32, XOR-swizzled). Tile 2i -> slots
// 0/1, tile 2i+1 -> slots 2/3. vmcnt(6) gates at ph3/ph7 only.  [FROZEN]
// ============================================================================

#define ST_B(GB, LD, SLOT, KC)                                                \
  _Pragma("unroll") for (int j_ = 0; j_ < 2; ++j_)                            \
    __builtin_amdgcn_global_load_lds(                                         \
        (g_u32*)((GB) + (srow + wid * 16 + j_ * 8 + (lane >> 3)) * (LD)       \
                 + (KC) + scg * 8),                                           \
        (l_u32*)(sh + (SLOT) * 16384 + 8192 + (wid * 16 + j_ * 8) * 64),      \
        16, 0, 0);

#define ST_A(GA, LD, SP, ST, KC)                                              \
    __builtin_amdgcn_global_load_lds(                                         \
        (g_u32*)((GA) + (srow + (ST) * 32 + (wid & 3) * 8 + (lane >> 3)) * (LD) \
                 + (KC) + (wid >> 2) * 32 + scg * 8),                         \
        (l_u32*)(sh + ((SP) + (wid >> 2)) * 16384 +                           \
                 ((ST) * 32 + (wid & 3) * 8) * 64),                           \
        16, 0, 0);

#define RD_A(S0, S1, Q)                                                       \
  a0[0] = *(const frag8*)(lds + (S0) * 16384 + tA + (Q) * 2048);              \
  a0[1] = *(const frag8*)(lds + (S0) * 16384 + tA + (Q) * 2048 + 1024);       \
  a1[0] = *(const frag8*)(lds + (S1) * 16384 + tA + (Q) * 2048);              \
  a1[1] = *(const frag8*)(lds + (S1) * 16384 + tA + (Q) * 2048 + 1024);

#define RD_B(D0, D1, S0, S1)                                                  \
  _Pragma("unroll") for (int n_ = 0; n_ < 4; ++n_) {                          \
    D0[n_] = *(const frag8*)(lds + (S0) * 16384 + tB + n_ * 1024);            \
    D1[n_] = *(const frag8*)(lds + (S1) * 16384 + tB + n_ * 1024);            \
  }

#define MM8(AQ, B0, B1)                                                       \
  __builtin_amdgcn_s_setprio(1);                                              \
  _Pragma("unroll") for (int j_ = 0; j_ < 2; ++j_)                            \
  _Pragma("unroll") for (int n_ = 0; n_ < 4; ++n_)                            \
    acc[(AQ) + j_][n_] = __builtin_amdgcn_mfma_f32_16x16x32_bf16(             \
        a0[j_], B0[n_], acc[(AQ) + j_][n_], 0, 0, 0);                         \
  _Pragma("unroll") for (int j_ = 0; j_ < 2; ++j_)                            \
  _Pragma("unroll") for (int n_ = 0; n_ < 4; ++n_)                            \
    acc[(AQ) + j_][n_] = __builtin_amdgcn_mfma_f32_16x16x32_bf16(             \
        a1[j_], B1[n_], acc[(AQ) + j_][n_], 0, 0, 0);                         \
  __builtin_amdgcn_s_setprio(0);

#define BAR __builtin_amdgcn_s_barrier()
#define LG0                                                                   \
  asm volatile("s_waitcnt lgkmcnt(0)" ::: "memory");                          \
  __builtin_amdgcn_sched_barrier(0)

// MODE: 0 = elu(v+bias[col])+1 -> bf16   (Q projection)
//       1 = elu(v+bias[row])+1 -> bf16, fused ksum (aux += row-sums)
//       2 = v+bias[row]        -> bf16   (V^T projection)
//       3 = v+bias[col]        -> f32    (final output projection)
template <int MODE, bool XMAJOR>
__global__ __launch_bounds__(512, 2) void gemm256_nt_kernel(
    const unsigned short* __restrict__ A, long lda,
    const unsigned short* __restrict__ Bm, long ldb,
    void* __restrict__ Cv, long ldc,
    const float* __restrict__ bias, float* __restrict__ aux, int K) {
  __shared__ unsigned short sh[65536];   // 128 KiB = 4 slots
  const int lane = threadIdx.x & 63, wid = threadIdx.x >> 6;
  const int wm = wid >> 2, wn = wid & 3;
  const int lr = lane & 15, lh = lane >> 4;

  // T1 bijective XCD swizzle
  const int gx = gridDim.x, gy = gridDim.y;
  const int cpx = (gx * gy) >> 3;
  const int P = blockIdx.y * gx + blockIdx.x;
  const int Lw = (P & 7) * cpx + (P >> 3);
  int bx, by;
  if (XMAJOR) { bx = Lw / gy; by = Lw - bx * gy; }
  else        { by = Lw / gx; bx = Lw - by * gx; }

  const long m0 = (long)by * 256, n0 = (long)bx * 256;
  const unsigned short* Ablk = A + m0 * lda;
  const unsigned short* Bblk = Bm + n0 * ldb;
  const int NT = K >> 6;

  const int qA = (wm * 4 + lh) ^ (lr & 7);
  const int qB = ((wn >> 1) * 4 + lh) ^ (lr & 7);
  const unsigned short* lds = sh;
  const int tA = lr * 64 + qA * 8;
  const int tB = 8192 + ((wn & 1) * 64 + lr) * 64 + qB * 8;

  const int sqd = (lane & 7) ^ (lane >> 3);
  const int scg = sqd & 3;
  const long srow = (long)((sqd >> 2) * 128);

  f32x4 acc[8][4];
#pragma unroll
  for (int m = 0; m < 8; ++m)
#pragma unroll
    for (int n = 0; n < 4; ++n) acc[m][n] = (f32x4){0.f, 0.f, 0.f, 0.f};

  frag8 a0[2], a1[2], bu0[4], bu1[4], bv0[4], bv1[4];

  // prologue: tile 0 complete (8 units), tile 1 all but A-strips 2,3
  ST_B(Bblk, ldb, 0, 0)
  ST_B(Bblk, ldb, 1, 32)
  ST_A(Ablk, lda, 0, 0, 0) ST_A(Ablk, lda, 0, 1, 0)
  ST_A(Ablk, lda, 0, 2, 0) ST_A(Ablk, lda, 0, 3, 0)
  if (NT > 1) {
    ST_B(Bblk, ldb, 2, 64)
    ST_B(Bblk, ldb, 3, 96)
    ST_A(Ablk, lda, 2, 0, 64) ST_A(Ablk, lda, 2, 1, 64)
  }
  asm volatile("s_waitcnt vmcnt(6)" ::: "memory");   // tile 0 landed
  BAR;

  const int NI = NT >> 1;
  for (int i = 0; i < NI; ++i) {
    const int kv = i * 128 + 64, kw = i * 128 + 128, kx = i * 128 + 192;
    const bool wok = (i + 1) < NI;
    // ---- ph0: tile u (slots 0,1) quadrant 0 ----
    RD_A(0, 1, 0)
    RD_B(bu0, bu1, 0, 1)
    ST_A(Ablk, lda, 2, 2, kv) ST_A(Ablk, lda, 2, 3, kv)
    asm volatile("s_waitcnt lgkmcnt(8)" ::: "memory");
    BAR; LG0;
    MM8(0, bu0, bu1)
    BAR;
    // ---- ph1: u q1 ----
    RD_A(0, 1, 1)
    if (wok) { ST_B(Bblk, ldb, 0, kw) }
    BAR; LG0;
    MM8(2, bu0, bu1)
    BAR;
    // ---- ph2: u q2 ----
    RD_A(0, 1, 2)
    if (wok) { ST_B(Bblk, ldb, 1, kw + 32) }
    BAR; LG0;
    MM8(4, bu0, bu1)
    BAR;
    // ---- ph3: u q3 ; vmcnt gate for tile v ----
    RD_A(0, 1, 3)
    if (wok) { ST_A(Ablk, lda, 0, 0, kw) ST_A(Ablk, lda, 0, 1, kw) }
    if (wok) asm volatile("s_waitcnt vmcnt(6)" ::: "memory");
    else     asm volatile("s_waitcnt vmcnt(0)" ::: "memory");
    BAR; LG0;
    MM8(6, bu0, bu1)
    BAR;
    // ---- ph4: tile v (slots 2,3) quadrant 0 ----
    RD_A(2, 3, 0)
    RD_B(bv0, bv1, 2, 3)
    if (wok) { ST_A(Ablk, lda, 0, 2, kw) ST_A(Ablk, lda, 0, 3, kw) }
    asm volatile("s_waitcnt lgkmcnt(8)" ::: "memory");
    BAR; LG0;
    MM8(0, bv0, bv1)
    BAR;
    // ---- ph5: v q1 ----
    RD_A(2, 3, 1)
    if (wok) { ST_B(Bblk, ldb, 2, kx) }
    BAR; LG0;
    MM8(2, bv0, bv1)
    BAR;
    // ---- ph6: v q2 ----
    RD_A(2, 3, 2)
    if (wok) { ST_B(Bblk, ldb, 3, kx + 32) }
    BAR; LG0;
    MM8(4, bv0, bv1)
    BAR;
    // ---- ph7: v q3 ; vmcnt gate for tile w (next iter) ----
    RD_A(2, 3, 3)
    if (wok) { ST_A(Ablk, lda, 2, 0, kx) ST_A(Ablk, lda, 2, 1, kx)
               asm volatile("s_waitcnt vmcnt(6)" ::: "memory"); }
    BAR; LG0;
    MM8(6, bv0, bv1)
    BAR;
  }

  // ---- epilogue (acc[m]: rows (m>>1)*32 + (m&1)*16 of the wave's 128) ----
  if constexpr (MODE == 1) {
    __shared__ float red2[256];
    if (threadIdx.x < 256) red2[threadIdx.x] = 0.f;
    __syncthreads();
#pragma unroll
    for (int m = 0; m < 8; ++m)
#pragma unroll
      for (int r = 0; r < 4; ++r) {
        const int lrow = wm * 128 + (m >> 1) * 32 + (m & 1) * 16 + lh * 4 + r;
        const long row = m0 + lrow;
        float part = 0.f;
#pragma unroll
        for (int n = 0; n < 4; ++n) {
          long col = n0 + wn * 64 + n * 16 + lr;
          float v = acc[m][n][r] + bias[row];
          v = v > 0.f ? v + 1.f : __expf(v);
          unsigned short us = f2bf(v);
          ((unsigned short*)Cv)[row * ldc + col] = us;
          part += bf2f(us);
        }
#pragma unroll
        for (int s = 1; s < 16; s <<= 1) part += __shfl_xor(part, s);
        if (lr == 0) atomicAdd(&red2[lrow], part);
      }
    __syncthreads();
    if (threadIdx.x < 256)
      atomicAdd(&aux[(n0 >> 12) * 2048 + m0 + threadIdx.x], red2[threadIdx.x]);
  } else {
#pragma unroll
    for (int m = 0; m < 8; ++m)
#pragma unroll
      for (int n = 0; n < 4; ++n)
#pragma unroll
        for (int r = 0; r < 4; ++r) {
          long row = m0 + wm * 128 + (m >> 1) * 32 + (m & 1) * 16 + lh * 4 + r;
          long col = n0 + wn * 64 + n * 16 + lr;
          float v = acc[m][n][r];
          if (MODE == 0) {
            v += bias[col]; v = v > 0.f ? v + 1.f : __expf(v);
            ((unsigned short*)Cv)[row * ldc + col] = f2bf(v);
          } else if (MODE == 2) {
            v += bias[row];
            ((unsigned short*)Cv)[row * ldc + col] = f2bf(v);
          } else {
            v += bias[col];
            ((float*)Cv)[row * ldc + col] = v;
          }
        }
  }
}

// ============================================================================
// 128x128 path (attention core).
// ============================================================================
__device__ __forceinline__ void stage_tile(const unsigned short* __restrict__ G,
                                           long ld, unsigned short* __restrict__ L) {
  const int w = threadIdx.x >> 6, l = threadIdx.x & 63;
#pragma unroll
  for (int r = 0; r < 4; ++r) {
    const int chunk = w * 4 + r;
    const int row = chunk * 8 + (l >> 3);
    const int col = (l & 7) * 8;
    __builtin_amdgcn_global_load_lds((g_u32*)(G + (long)row * ld + col),
                                     (l_u32*)(L + chunk * 512), 16, 0, 0);
  }
}

__device__ __forceinline__ void gemm_mainloop(const unsigned short* __restrict__ A, long lda,
                                              const unsigned short* __restrict__ B, long ldb,
                                              int K, unsigned short* lA, unsigned short* lB,
                                              f32x4 acc[4][4]) {
  const int lane = threadIdx.x & 63;
  const int wid  = threadIdx.x >> 6;
  const int wr = wid >> 1, wc = wid & 1;
  const int lr = lane & 15, lh = lane >> 4;
  for (int k0 = 0; k0 < K; k0 += 64) {
    stage_tile(A + k0, lda, lA);
    stage_tile(B + k0, ldb, lB);
    __syncthreads();
#pragma unroll
    for (int kk = 0; kk < 64; kk += 32) {
      frag8 av[4], bv[4];
#pragma unroll
      for (int m = 0; m < 4; ++m)
        av[m] = *reinterpret_cast<const frag8*>(lA + (wr * 64 + m * 16 + lr) * 64 + kk + lh * 8);
#pragma unroll
      for (int n = 0; n < 4; ++n)
        bv[n] = *reinterpret_cast<const frag8*>(lB + (wc * 64 + n * 16 + lr) * 64 + kk + lh * 8);
#pragma unroll
      for (int m = 0; m < 4; ++m)
#pragma unroll
        for (int n = 0; n < 4; ++n)
          acc[m][n] = __builtin_amdgcn_mfma_f32_16x16x32_bf16(av[m], bv[n], acc[m][n], 0, 0, 0);
    }
    __syncthreads();
  }
}

#define ACC_INIT(acc)                                   \
  _Pragma("unroll") for (int m_ = 0; m_ < 4; ++m_)      \
  _Pragma("unroll") for (int n_ = 0; n_ < 4; ++n_)      \
      acc[m_][n_] = (f32x4){0.f, 0.f, 0.f, 0.f};

// ---- KV^T partials ---------------------------------------------------------
__global__ __launch_bounds__(256) void kvt_partial_kernel(
    const unsigned short* __restrict__ VT, const unsigned short* __restrict__ KT,
    float* __restrict__ part) {
  __shared__ unsigned short lA[128 * 64], lB[128 * 64];
  const int z = blockIdx.x;            // 0..511 = bh*8 + chunk
  const int bh = z >> 3, c = z & 7;
  const int b = bh >> 4, h = bh & 15;
  const long tOff = (long)b * SEQ + (long)c * 512;
  const unsigned short* A  = VT + (long)(h * DKH) * M_TOK + tOff;
  const unsigned short* Bm = KT + (long)(h * DKH) * M_TOK + tOff;
  f32x4 acc[4][4];
  ACC_INIT(acc);
  gemm_mainloop(A, M_TOK, Bm, M_TOK, 512, lA, lB, acc);
  const int lane = threadIdx.x & 63, wid = threadIdx.x >> 6;
  const int wr = wid >> 1, wc = wid & 1, lr = lane & 15, lh = lane >> 4;
  float* out = part + (long)z * (DKH * DKH);
#pragma unroll
  for (int m = 0; m < 4; ++m)
#pragma unroll
    for (int n = 0; n < 4; ++n)
#pragma unroll
      for (int r = 0; r < 4; ++r) {
        int row = wr * 64 + m * 16 + lh * 4 + r;   // e
        int col = wc * 64 + n * 16 + lr;           // d
        out[row * DKH + col] = acc[m][n][r];
      }
}

__global__ __launch_bounds__(256) void reduce_kvt_kernel(
    const float* __restrict__ part, unsigned short* __restrict__ kvt) {
  int i = blockIdx.x * 256 + threadIdx.x;          // over 64*16384
  if (i < NBH * DKH * DKH) {
    int bh = i >> 14, j = i & 16383;
    float s = 0.f;
#pragma unroll
    for (int c = 0; c < 8; ++c) s += part[(((long)bh * 8 + c) << 14) + j];
    kvt[i] = f2bf(s);
  }
}

// ---- QKV + fused qsum, 4 m-tiles per block ---------------------------------
// Block (mc, z): rows [mc*512, mc*512+512) of head z. KVT staged once (32KB),
// then 4 m-tiles of 128 rows: stage Q-tile (both 64-col halves), qsum from
// staged LDS, MFMA over K=128, divide, store.
__global__ __launch_bounds__(256) void qkv_kernel(const unsigned short* __restrict__ Q,
                                                  const unsigned short* __restrict__ KVT,
                                                  const float* __restrict__ ksum,
                                                  unsigned short* __restrict__ attn) {
  __shared__ unsigned short lA[2][128 * 64], lB[2][128 * 64];
  __shared__ float qs[128];
  const int z = blockIdx.y, b = z >> 4, h = z & 15;
  const long mbase = (long)blockIdx.x * 512;
  const unsigned short* Bm = KVT + (long)z * (DKH * DKH);
  const float* ks = ksum + (long)b * 2048 + h * DKH;
  const int lane = threadIdx.x & 63, wid = threadIdx.x >> 6;
  const int wr = wid >> 1, wc = wid & 1, lr = lane & 15, lh = lane >> 4;
  const int qrow = threadIdx.x >> 1, qhalf = threadIdx.x & 1;

  stage_tile(Bm,      DKH, lB[0]);
  stage_tile(Bm + 64, DKH, lB[1]);

  for (int mt = 0; mt < 4; ++mt) {
    const unsigned short* A = Q + ((long)b * SEQ + mbase + mt * 128) * D_MODEL + h * DKH;
    stage_tile(A,      D_MODEL, lA[0]);
    stage_tile(A + 64, D_MODEL, lA[1]);
    __syncthreads();   // A-tile (and B on first iter) visible to all
    // qsum partial: 2 threads per row, 64 elems each (one 64-col half)
    float qacc = 0.f;
    {
      const unsigned* pr = (const unsigned*)(lA[qhalf] + qrow * 64);
      const float* kk = ks + qhalf * 64;
#pragma unroll
      for (int j = 0; j < 32; ++j) {
        unsigned u = pr[j];
        qacc += bf2f((unsigned short)(u & 0xffff)) * kk[2 * j] +
                bf2f((unsigned short)(u >> 16)) * kk[2 * j + 1];
      }
    }
    qacc += __shfl_xor(qacc, 1);
    if (qhalf == 0) qs[qrow] = qacc;
    f32x4 acc[4][4];
    ACC_INIT(acc);
#pragma unroll
    for (int hf = 0; hf < 2; ++hf)
#pragma unroll
      for (int kk2 = 0; kk2 < 64; kk2 += 32) {
        frag8 av[4], bv[4];
#pragma unroll
        for (int m = 0; m < 4; ++m)
          av[m] = *reinterpret_cast<const frag8*>(lA[hf] + (wr * 64 + m * 16 + lr) * 64 + kk2 + lh * 8);
#pragma unroll
        for (int n = 0; n < 4; ++n)
          bv[n] = *reinterpret_cast<const frag8*>(lB[hf] + (wc * 64 + n * 16 + lr) * 64 + kk2 + lh * 8);
#pragma unroll
        for (int m = 0; m < 4; ++m)
#pragma unroll
          for (int n = 0; n < 4; ++n)
            acc[m][n] = __builtin_amdgcn_mfma_f32_16x16x32_bf16(av[m], bv[n], acc[m][n], 0, 0, 0);
      }
    __syncthreads();   // qs visible; all lA reads complete (safe to restage)
#pragma unroll
    for (int m = 0; m < 4; ++m)
#pragma unroll
      for (int n = 0; n < 4; ++n)
#pragma unroll
        for (int r = 0; r < 4; ++r) {
          const int lrow = wr * 64 + m * 16 + lh * 4 + r;
          const long row = mbase + mt * 128 + lrow;        // s in [0,4096)
          const int col = wc * 64 + n * 16 + lr;           // e in [0,128)
          float dnm = qs[lrow] + 1e-8f;
          float v = acc[m][n][r] / dnm;
          attn[((long)b * SEQ + row) * D_MODEL + h * DKH + col] = f2bf(v);
        }
  }
}

// ---- workspace layout (bytes) ----------------------------------------------
#define OFF_XB   0L
#define OFF_WQ   (OFF_XB + (long)M_TOK * D_MODEL * 2)
#define OFF_WK   (OFF_WQ + (long)D_MODEL * D_MODEL * 2)
#define OFF_WV   (OFF_WK + (long)D_MODEL * D_MODEL * 2)
#define OFF_WO   (OFF_WV + (long)D_MODEL * D_MODEL * 2)
#define OFF_QB   (OFF_WO + (long)D_MODEL * D_MODEL * 2)
#define OFF_KT   (OFF_QB + (long)M_TOK * D_MODEL * 2)
#define OFF_VT   (OFF_KT + (long)M_TOK * D_MODEL * 2)
#define OFF_PART (OFF_VT + (long)M_TOK * D_MODEL * 2)
#define OFF_KVT  (OFF_PART + (long)512 * DKH * DKH * 4)
#define OFF_KSUM (OFF_KVT + (long)NBH * DKH * DKH * 2)
#define OFF_QSUM (OFF_KSUM + (long)NBH * DKH * 4)
#define OFF_ATTN OFF_XB   // alias: x_bf16 dead after V^T projection

extern "C" void kernel_launch(void* const* d_in, const int* in_sizes, int n_in,
                              void* d_out, int out_size, void* d_ws, size_t ws_size,
                              hipStream_t stream) {
  const float* x  = (const float*)d_in[0];
  const float* wq = (const float*)d_in[1];
  const float* bq = (const float*)d_in[2];
  const float* wk = (const float*)d_in[3];
  const float* bk = (const float*)d_in[4];
  const float* wv = (const float*)d_in[5];
  const float* bv = (const float*)d_in[6];
  const float* wo = (const float*)d_in[7];
  const float* bo = (const float*)d_in[8];

  char* ws = (char*)d_ws;
  unsigned short* xb   = (unsigned short*)(ws + OFF_XB);
  unsigned short* wqb  = (unsigned short*)(ws + OFF_WQ);
  unsigned short* wkb  = (unsigned short*)(ws + OFF_WK);
  unsigned short* wvb  = (unsigned short*)(ws + OFF_WV);
  unsigned short* wob  = (unsigned short*)(ws + OFF_WO);
  unsigned short* Qb   = (unsigned short*)(ws + OFF_QB);
  unsigned short* KTb  = (unsigned short*)(ws + OFF_KT);
  unsigned short* VTb  = (unsigned short*)(ws + OFF_VT);
  float*          part = (float*)(ws + OFF_PART);
  unsigned short* KVTb = (unsigned short*)(ws + OFF_KVT);
  float*          ksum = (float*)(ws + OFF_KSUM);
  unsigned short* attn = (unsigned short*)(ws + OFF_ATTN);

  dim3 blk(256);
  dim3 blk5(512);

  // fp32 -> bf16, all tensors in one launch
  convert_all_kernel<<<49152, blk, 0, stream>>>(x, wq, wk, wv, wo,
                                                xb, wqb, wkb, wvb, wob);

  // ksum must start at zero (K^T-proj accumulates into it)
  hipMemsetAsync(ksum, 0, NBH * DKH * sizeof(float), stream);

  // Q = elu(x@Wq^T + bq)+1   (lean epilogue)
  gemm256_nt_kernel<0, false><<<dim3(D_MODEL / 256, M_TOK / 256), blk5, 0, stream>>>(
      xb, D_MODEL, wqb, D_MODEL, Qb, D_MODEL, bq, nullptr, D_MODEL);
  // K^T = elu(Wk@x^T + bk)+1  (2048 x M_TOK), fused ksum
  gemm256_nt_kernel<1, true><<<dim3(M_TOK / 256, D_MODEL / 256), blk5, 0, stream>>>(
      wkb, D_MODEL, xb, D_MODEL, KTb, M_TOK, bk, ksum, D_MODEL);
  // V^T = Wv@x^T + bv
  gemm256_nt_kernel<2, true><<<dim3(M_TOK / 256, D_MODEL / 256), blk5, 0, stream>>>(
      wvb, D_MODEL, xb, D_MODEL, VTb, M_TOK, bv, nullptr, D_MODEL);

  // KV^T per (b,h) via split-K partials + reduce
  kvt_partial_kernel<<<512, blk, 0, stream>>>(VTb, KTb, part);
  reduce_kvt_kernel<<<(NBH * DKH * DKH) / 256, blk, 0, stream>>>(part, KVTb);

  // attn = (Q @ KV) / (Q . Ksum + 1e-8)   -> bf16 (aliases xb); qsum fused
  qkv_kernel<<<dim3(SEQ / 512, NBH), blk, 0, stream>>>(Qb, KVTb, ksum, attn);

  // out = attn @ Wo^T + bo  -> fp32
  gemm256_nt_kernel<3, false><<<dim3(D_MODEL / 256, M_TOK / 256), blk5, 0, stream>>>(
      attn, D_MODEL, wob, D_MODEL, d_out, D_MODEL, bo, nullptr, D_MODEL);
}